// Round 9
// baseline (2754.659 us; speedup 1.0000x reference)
//
#include <hip/hip_runtime.h>
#include <hip/hip_cooperative_groups.h>

namespace cg = cooperative_groups;

// DGMC: B=4, NS=NT=512, D_IN=128, C1=64, R=C2=32, E=32768, STEPS=10
// r23: persistent cooperative step-loop. Model (r15-r22): step work ~5us,
// ~7us per dispatch boundary x ~40 boundaries dominates; every kernel-
// reshape attempt to remove boundaries lost (r17/r18 occupancy, r20/r21
// scattered reads, r22 gather widening). So keep EXACT r19 phase shapes
// (512 blocks x 256 thr each) and replace kernel boundaries with
// grid.sync() in ONE cooperative kernel. Fallback to identical
// multi-kernel sequence if cooperative launch is refused.
// Lessons: no per-block device fences/atomics in hot kernels (r3/r15);
// coalesce or LDS-stage per-thread-row access (r17); don't concentrate
// work into few low-occupancy blocks (r18/r21); never widen/deepen the
// critical gather (r6/r10/r22); 8-deep gather ILP (r12); many cheap waves
// > few wide (r14); parallel CSR (r9).

constexpr int kB = 4;
constexpr int kNS = 512;
constexpr int kNT = 512;
constexpr int kDin = 128;
constexpr int kC1 = 64;
constexpr int kR = 32;
constexpr int kC2 = 32;
constexpr int kE = 32768;
constexpr int kSteps = 10;
constexpr int kN = kB * kNS;              // 2048 nodes per side
constexpr int kEP = kE + 16 * kN;         // padded CSR capacity per graph
constexpr int kChunkStride = kR * kN;     // floats per rt partial chunk (65536)
constexpr int kSmemF = 8488;              // union: upd(8448+32+8) > rt(4224)

// ---------------- CSR build (parallel, 3 kernels + memset) ----------------
__global__ void k_hist(const int* __restrict__ ei_s, const int* __restrict__ ei_t,
                       int* __restrict__ deg) {
  int g = blockIdx.y;
  const int* dst = (g ? ei_t : ei_s) + kE;
  int e = blockIdx.x * 256 + threadIdx.x;
  atomicAdd(&deg[g * kN + dst[e]], 1);
}

__global__ void k_scan(const int* __restrict__ deg, int* __restrict__ off,
                       int* __restrict__ cur) {
  int g = blockIdx.x;
  const int* d = deg + g * kN;
  int* o = off + g * (kN + 1);
  int* c = cur + g * kN;
  __shared__ int sums[256];
  int tid = threadIdx.x;
  int loc[8];
  int s = 0;
#pragma unroll
  for (int i = 0; i < 8; ++i) {
    loc[i] = (d[tid * 8 + i] + 15) & ~15;  // pad to x16
    s += loc[i];
  }
  sums[tid] = s;
  __syncthreads();
  for (int st = 1; st < 256; st <<= 1) {
    int v = (tid >= st) ? sums[tid - st] : 0;
    __syncthreads();
    sums[tid] += v;
    __syncthreads();
  }
  int base = (tid > 0) ? sums[tid - 1] : 0;
#pragma unroll
  for (int i = 0; i < 8; ++i) {
    int idx = tid * 8 + i;
    o[idx] = base;
    c[idx] = base;
    base += loc[i];
  }
  if (tid == 255) o[kN] = base;
}

__global__ void k_scatter(const int* __restrict__ ei_s, const int* __restrict__ ei_t,
                          const float* __restrict__ ea_s, const float* __restrict__ ea_t,
                          int* __restrict__ cur, int* __restrict__ srcs,
                          float* __restrict__ eaw) {
  int g = blockIdx.y;
  const int* ei = g ? ei_t : ei_s;
  const float* ea = g ? ea_t : ea_s;
  int e = blockIdx.x * 256 + threadIdx.x;
  int d = ei[kE + e];
  int srcv = ei[e];
  int pos = atomicAdd(&cur[g * kN + d], 1);
  srcs[g * kEP + pos] = srcv;
  eaw[g * kEP + pos] = ea[e];
}

// ---------------- psi2 core (1 wave per node, no LDS) ----------------
__device__ __forceinline__ void psi2_node(
    int n, const float* __restrict__ vin, const int* __restrict__ sr,
    const float* __restrict__ ew, const int* __restrict__ o,
    const float* __restrict__ W2, const float* __restrict__ mw1,
    const float* __restrict__ mb1, const float* __restrict__ mw2w,
    float* __restrict__ Pout, float* __restrict__ ctOut) {
  int lane = threadIdx.x & 63;
  int f = lane & 31, hh = lane >> 5;
  int beg = o[n], end = o[n + 1];
  float m = 0.f;
  for (int b0 = beg + hh * 8; b0 < end; b0 += 16) {
#pragma unroll
    for (int q = 0; q < 8; ++q)
      m += vin[(size_t)sr[b0 + q] * kR + f] * ew[b0 + q];
  }
  m += __shfl_down(m, 32, 64);
  float v = vin[(size_t)n * kR + f] + m;  // valid on lanes 0..31
  float acc = 0.f;
#pragma unroll
  for (int k = 0; k < kC2; ++k) acc += __shfl(v, k, 64) * W2[k * kC2 + f];
  float ov = fmaxf(acc, 0.f);
  float p = mb1 ? mb1[f] : 0.f;
#pragma unroll
  for (int k = 0; k < kC2; ++k) p += __shfl(ov, k, 64) * mw1[k * kC2 + f];
  if (lane < 32) Pout[(size_t)n * kC2 + f] = p;
  if (ctOut) {
    float c = p * mw2w[f];  // p duplicated on lanes 32..63 (same f)
#pragma unroll
    for (int o2 = 16; o2; o2 >>= 1) c += __shfl_xor(c, o2, 64);
    if (lane == 0) ctOut[n] = c;
  }
}

// ---- fused pre-kernel: blocks [0,2048) = psi1; [2048,7168) = psi2s ----
__global__ __launch_bounds__(256) void k_pre(
    const float* __restrict__ x_s, const float* __restrict__ x_t,
    const float* __restrict__ r, const int* __restrict__ srcs,
    const float* __restrict__ eaw, const int* __restrict__ off,
    const float* __restrict__ W1, const float* __restrict__ W2,
    const float* __restrict__ mw1, const float* __restrict__ mb1,
    float* __restrict__ h, float* __restrict__ PsAll) {
  int bid = blockIdx.x, tid = threadIdx.x;
  if (bid < 2048) {
    int g = bid >> 10;                 // side
    int n = (bid & 1023) * 2 + (tid >> 7);
    int f = tid & 127;
    const float* x = g ? x_t : x_s;
    const int* sr = srcs + g * kEP;
    const float* ew = eaw + g * kEP;
    const int* o = off + g * (kN + 1);
    float* ho = h + (size_t)g * kN * kC1;
    __shared__ float y[2][kDin];
    int beg = o[n], end = o[n + 1];
    float xself = x[(size_t)n * kDin + f];
    float m = 0.f;
    for (int idx = beg; idx < end; idx += 8) {
      float a0 = x[(size_t)sr[idx + 0] * kDin + f] * ew[idx + 0];
      float a1 = x[(size_t)sr[idx + 1] * kDin + f] * ew[idx + 1];
      float a2 = x[(size_t)sr[idx + 2] * kDin + f] * ew[idx + 2];
      float a3 = x[(size_t)sr[idx + 3] * kDin + f] * ew[idx + 3];
      float a4 = x[(size_t)sr[idx + 4] * kDin + f] * ew[idx + 4];
      float a5 = x[(size_t)sr[idx + 5] * kDin + f] * ew[idx + 5];
      float a6 = x[(size_t)sr[idx + 6] * kDin + f] * ew[idx + 6];
      float a7 = x[(size_t)sr[idx + 7] * kDin + f] * ew[idx + 7];
      m += ((a0 + a1) + (a2 + a3)) + ((a4 + a5) + (a6 + a7));
    }
    y[tid >> 7][f] = xself + m;
    __syncthreads();
    if (f < kC1) {
      const float* yy = y[tid >> 7];
      float acc = 0.f;
#pragma unroll 16
      for (int k = 0; k < kDin; ++k) acc += yy[k] * W1[k * kC1 + f];
      ho[(size_t)n * kC1 + f] = fmaxf(acc, 0.f);
    }
  } else {
    int nn = (bid - 2048) * 4 + (tid >> 6);  // 0..20479
    int step = nn >> 11, node = nn & (kN - 1);
    psi2_node(node, r + (size_t)step * kN * kR, srcs, eaw, off, W2, mw1, mb1,
              nullptr, PsAll + (size_t)step * kN * kR, nullptr);
  }
}

// ------- S_hat0 = h_s @ h_t^T; emits 8-chunk row stats (64-col chunks) ----
__global__ __launch_bounds__(256) void k_shat0(const float* __restrict__ h,
                                               float* __restrict__ Shat,
                                               float* __restrict__ pstatm,
                                               float* __restrict__ pstatl) {
  int b = blockIdx.z, s0 = blockIdx.y * 64, t0 = blockIdx.x * 64;
  const float* hs = h + (size_t)(b * kNS + s0) * kC1;
  const float* ht = h + (size_t)kN * kC1 + (size_t)(b * kNT + t0) * kC1;
  __shared__ float As[64 * 68];
  __shared__ float Bs[64 * 68];
  int tid = threadIdx.x;
#pragma unroll
  for (int k2 = 0; k2 < 4; ++k2) {
    int idx = tid + k2 * 256;
    int row = idx >> 4, c4 = idx & 15;
    float4 va = *(const float4*)(hs + (size_t)row * kC1 + c4 * 4);
    *(float4*)&As[row * 68 + c4 * 4] = va;
    float4 vb = *(const float4*)(ht + (size_t)row * kC1 + c4 * 4);
    *(float4*)&Bs[row * 68 + c4 * 4] = vb;
  }
  __syncthreads();
  int ts = tid >> 4, tt = tid & 15;
  float acc[4][4] = {};
#pragma unroll
  for (int cc = 0; cc < 16; ++cc) {
    float4 a[4], bt[4];
#pragma unroll
    for (int i = 0; i < 4; ++i) a[i] = *(const float4*)&As[(ts * 4 + i) * 68 + cc * 4];
#pragma unroll
    for (int k = 0; k < 4; ++k) bt[k] = *(const float4*)&Bs[(tt + 16 * k) * 68 + cc * 4];
#pragma unroll
    for (int i = 0; i < 4; ++i)
#pragma unroll
      for (int k = 0; k < 4; ++k)
        acc[i][k] += a[i].x * bt[k].x + a[i].y * bt[k].y + a[i].z * bt[k].z + a[i].w * bt[k].w;
  }
#pragma unroll
  for (int i = 0; i < 4; ++i) {
    int s = s0 + ts * 4 + i;
    float* row = Shat + (size_t)(b * kNS + s) * kNT;
#pragma unroll
    for (int k = 0; k < 4; ++k) row[t0 + tt + 16 * k] = acc[i][k];
  }
#pragma unroll
  for (int i = 0; i < 4; ++i) {
    float mm = fmaxf(fmaxf(acc[i][0], acc[i][1]), fmaxf(acc[i][2], acc[i][3]));
#pragma unroll
    for (int o2 = 8; o2; o2 >>= 1) mm = fmaxf(mm, __shfl_xor(mm, o2, 64));
    float se = 0.f;
#pragma unroll
    for (int k = 0; k < 4; ++k) se += __expf(acc[i][k] - mm);
#pragma unroll
    for (int o2 = 8; o2; o2 >>= 1) se += __shfl_xor(se, o2, 64);
    if (tt == 0) {
      int grow = b * kNS + s0 + ts * 4 + i;
      pstatm[blockIdx.x * kN + grow] = mm;
      pstatl[blockIdx.x * kN + grow] = se;
    }
  }
}

// ================= phase device functions (exact r19 shapes) =================
// bid in [0,512); 256 threads.

// rt partials: bid = b*128 + cs*16 + tx  (b<4, cs<8, tx<16; t0 = tx*32)
__device__ __forceinline__ void phase_rt(
    int bid, const float* __restrict__ Shat, const float* pstatm,
    const float* pstatl, const float* __restrict__ ri, float* __restrict__ part,
    int nc, float* __restrict__ Sout, float* smem) {
  int b = bid >> 7, rem = bid & 127;
  int cs = rem >> 4, t0 = (rem & 15) * 32;
  int s0 = cs * 64;
  float* Wt = smem;                 // 64*32
  float* rch = smem + 2048;         // 64*32
  float* lm = smem + 4096;          // 64
  float* ll = smem + 4160;          // 64
  int tid = threadIdx.x;
  if (tid < 64) {
    int row = b * kNS + s0 + tid;
    float m = -3.4e38f;
    for (int c = 0; c < nc; ++c) m = fmaxf(m, pstatm[c * kN + row]);
    float l = 0.f;
    for (int c = 0; c < nc; ++c) l += __expf(pstatm[c * kN + row] - m) * pstatl[c * kN + row];
    lm[tid] = m;
    ll[tid] = 1.f / l;
  }
  __syncthreads();
#pragma unroll
  for (int k2 = 0; k2 < 2; ++k2) {
    int idx = tid + k2 * 256;          // 512 f4 = 64 rows x 32 cols
    int row = idx >> 3, c4 = idx & 7;
    int grow = b * kNS + s0 + row;
    float4 v = *(const float4*)(Shat + (size_t)grow * kNT + t0 + c4 * 4);
    float m = lm[row], l = ll[row];
    float4 wv;
    wv.x = __expf(v.x - m) * l;
    wv.y = __expf(v.y - m) * l;
    wv.z = __expf(v.z - m) * l;
    wv.w = __expf(v.w - m) * l;
    *(float4*)&Wt[row * 32 + c4 * 4] = wv;
    if (Sout) *(float4*)(Sout + (size_t)grow * kNT + t0 + c4 * 4) = wv;
    float4 rv = *(const float4*)(ri + (size_t)grow * kR + c4 * 4);
    *(float4*)&rch[row * 32 + c4 * 4] = rv;
  }
  __syncthreads();
  int t_l = tid & 31, jg = tid >> 5;   // 32 cols x 8 j-groups (4 j each)
  float4 acc = make_float4(0.f, 0.f, 0.f, 0.f);
  for (int s = 0; s < 64; ++s) {
    float wv = Wt[s * 32 + t_l];
    float4 rv = *(const float4*)&rch[s * 32 + jg * 4];
    acc.x += wv * rv.x; acc.y += wv * rv.y; acc.z += wv * rv.z; acc.w += wv * rv.w;
  }
  int gcol = b * kNT + t0 + t_l;
  float* dst = part + (size_t)cs * kChunkStride + (size_t)jg * 4 * kN + gcol;
  dst[0] = acc.x;
  dst[(size_t)kN] = acc.y;
  dst[(size_t)2 * kN] = acc.z;
  dst[(size_t)3 * kN] = acc.w;
  __syncthreads();                    // smem reused by next phase
}

__device__ __forceinline__ void phase_red(int bid, const float* __restrict__ part,
                                          float* __restrict__ rt) {
  int tid = threadIdx.x;
  if (tid < 128) {
    int idx = bid * 128 + tid;        // 65536 = 32 j x 2048 cols
    int j = idx >> 11, col = idx & (kN - 1);
    float s = 0.f;
#pragma unroll
    for (int cs = 0; cs < 8; ++cs) s += part[(size_t)cs * kChunkStride + idx];
    rt[(size_t)col * kR + j] = s;
  }
}

__device__ __forceinline__ void phase_psi2t(
    int bid, const float* __restrict__ rt, const int* __restrict__ srcs,
    const float* __restrict__ eaw, const int* __restrict__ off,
    const float* __restrict__ W2, const float* __restrict__ mw1,
    const float* __restrict__ mw2, float* __restrict__ Pt, float* __restrict__ ct) {
  int n = bid * 4 + (threadIdx.x >> 6);   // 4 nodes/block, 1 wave each, no LDS
  psi2_node(n, rt, srcs + kEP, eaw + kEP, off + (kN + 1), W2, mw1, nullptr,
            mw2, Pt, ct);
}

// upd: bid = sblk*2 + cc (sblk<256, cc<2)
__device__ __forceinline__ void phase_upd(
    int bid, float* __restrict__ Shat, const float* __restrict__ Ps,
    const float* __restrict__ Pt, const float* __restrict__ ctb,
    const float* __restrict__ mw2, const float* __restrict__ mb2,
    float* pstatm, float* pstatl, float* smem) {
  float* pts = smem;                // 256*33
  float* red = smem + 8448;         // 32
  float* lmx = smem + 8480;         // 8
  int tid = threadIdx.x;
  int g0 = (bid >> 1) * 8;   // global s-row base
  int cc = bid & 1;          // col chunk
  int bb = g0 >> 9;          // batch
  int c0 = cc * 256;
  const float4* PtB = (const float4*)(Pt + ((size_t)bb * kNT + c0) * kC2);
#pragma unroll
  for (int k = 0; k < 8; ++k) {
    int idx = tid + k * 256;  // 2048 float4
    int col = idx >> 3, q = idx & 7;
    float4 v = PtB[idx];
    float* d = &pts[col * 33 + q * 4];
    d[0] = v.x; d[1] = v.y; d[2] = v.z; d[3] = v.w;
  }
  float old[8];
#pragma unroll
  for (int s = 0; s < 8; ++s) old[s] = Shat[(size_t)(g0 + s) * kNT + c0 + tid];
  float ctv = ctb[(size_t)bb * kNT + c0 + tid];
  __syncthreads();
  float pt[32];
#pragma unroll
  for (int j = 0; j < 32; ++j) pt[j] = pts[tid * 33 + j];
  float bias = mb2[0] - ctv;
  float nv[8];
#pragma unroll
  for (int s = 0; s < 8; ++s) {
    const float* psr = Ps + (size_t)(g0 + s) * kC2;
    float u = 0.f;
#pragma unroll
    for (int j = 0; j < 32; ++j) u += fmaxf(psr[j], pt[j]) * mw2[j];
    float v = old[s] + u + bias;
    Shat[(size_t)(g0 + s) * kNT + c0 + tid] = v;
    nv[s] = v;
  }
  int wv = tid >> 6, ln = tid & 63;
#pragma unroll
  for (int s = 0; s < 8; ++s) {
    float m = nv[s];
#pragma unroll
    for (int o2 = 32; o2; o2 >>= 1) m = fmaxf(m, __shfl_down(m, o2, 64));
    if (ln == 0) red[s * 4 + wv] = m;
  }
  __syncthreads();
  if (tid < 8) {
    lmx[tid] = fmaxf(fmaxf(red[tid * 4], red[tid * 4 + 1]),
                     fmaxf(red[tid * 4 + 2], red[tid * 4 + 3]));
  }
  __syncthreads();
#pragma unroll
  for (int s = 0; s < 8; ++s) {
    float e = __expf(nv[s] - lmx[s]);
#pragma unroll
    for (int o2 = 32; o2; o2 >>= 1) e += __shfl_down(e, o2, 64);
    if (ln == 0) red[s * 4 + wv] = e;
  }
  __syncthreads();
  if (tid < 8) {
    float l = red[tid * 4] + red[tid * 4 + 1] + red[tid * 4 + 2] + red[tid * 4 + 3];
    pstatm[cc * kN + g0 + tid] = lmx[tid];
    pstatl[cc * kN + g0 + tid] = l;
  }
  __syncthreads();                    // smem reused by next phase
}

__device__ __forceinline__ void phase_out(
    int bid, const float* __restrict__ Shat, const float* pstatm,
    const float* pstatl, float* __restrict__ out) {
  int w = threadIdx.x >> 6, lane = threadIdx.x & 63;
  int row = bid * 4 + w;
  float m0 = pstatm[row], m1 = pstatm[kN + row];
  float l0 = pstatl[row], l1 = pstatl[kN + row];
  float m = fmaxf(m0, m1);
  float linv = 1.f / (__expf(m0 - m) * l0 + __expf(m1 - m) * l1);
  const float* p = Shat + (size_t)row * kNT;
  float* d = out + (size_t)row * kNT;
#pragma unroll
  for (int c = 0; c < kNT / 64; ++c) {
    int col = lane + c * 64;
    d[col] = __expf(p[col] - m) * linv;
  }
}

// ================= cooperative persistent step-loop kernel =================
__global__ __launch_bounds__(256, 2) void k_steps(
    float* Shat, float* pstatm, float* pstatl, const float* r,
    const float* PsAll, const int* srcs, const float* eaw, const int* off,
    const float* W2, const float* mw1, const float* mw2, const float* mb2,
    float* part, float* rt, float* Pt, float* ct, float* outS0, float* outSL) {
  cg::grid_group grid = cg::this_grid();
  __shared__ float smem[kSmemF];
  int bid = blockIdx.x;
  // initial: combine 8 stat chunks, write S_0, emit rt partials
  phase_rt(bid, Shat, pstatm, pstatl, r, part, 8, outS0, smem);
  grid.sync();
  phase_red(bid, part, rt);
  grid.sync();
  for (int i = 0; i < kSteps; ++i) {
    phase_psi2t(bid, rt, srcs, eaw, off, W2, mw1, mw2, Pt, ct);
    grid.sync();
    phase_upd(bid, Shat, PsAll + (size_t)i * kN * kR, Pt, ct, mw2, mb2,
              pstatm, pstatl, smem);
    grid.sync();
    if (i + 1 < kSteps) {
      phase_rt(bid, Shat, pstatm, pstatl, r + (size_t)(i + 1) * kN * kR,
               part, 2, nullptr, smem);
      grid.sync();
      phase_red(bid, part, rt);
      grid.sync();
    }
  }
  phase_out(bid, Shat, pstatm, pstatl, outSL);
}

// ================= fallback wrappers (identical phase code) =================
__global__ __launch_bounds__(256) void g_rt(const float* Shat, const float* pstatm,
                                            const float* pstatl, const float* ri,
                                            float* part, int nc, float* Sout) {
  __shared__ float smem[kSmemF];
  int bid = blockIdx.z * 128 + blockIdx.y * 16 + blockIdx.x;
  phase_rt(bid, Shat, pstatm, pstatl, ri, part, nc, Sout, smem);
}
__global__ __launch_bounds__(256) void g_red(const float* part, float* rt) {
  phase_red(blockIdx.x, part, rt);
}
__global__ __launch_bounds__(256) void g_psi2t(const float* rt, const int* srcs,
                                               const float* eaw, const int* off,
                                               const float* W2, const float* mw1,
                                               const float* mw2, float* Pt, float* ct) {
  phase_psi2t(blockIdx.x, rt, srcs, eaw, off, W2, mw1, mw2, Pt, ct);
}
__global__ __launch_bounds__(256) void g_upd(float* Shat, const float* Ps,
                                             const float* Pt, const float* ctb,
                                             const float* mw2, const float* mb2,
                                             float* pstatm, float* pstatl) {
  __shared__ float smem[kSmemF];
  phase_upd(blockIdx.x, Shat, Ps, Pt, ctb, mw2, mb2, pstatm, pstatl, smem);
}
__global__ __launch_bounds__(256) void g_out(const float* Shat, const float* pstatm,
                                             const float* pstatl, float* out) {
  phase_out(blockIdx.x, Shat, pstatm, pstatl, out);
}

extern "C" void kernel_launch(void* const* d_in, const int* in_sizes, int n_in,
                              void* d_out, int out_size, void* d_ws, size_t ws_size,
                              hipStream_t stream) {
  (void)in_sizes; (void)n_in; (void)out_size; (void)ws_size;
  const float* x_s = (const float*)d_in[0];
  const int* ei_s = (const int*)d_in[1];
  const float* ea_s = (const float*)d_in[2];
  const float* x_t = (const float*)d_in[4];
  const int* ei_t = (const int*)d_in[5];
  const float* ea_t = (const float*)d_in[6];
  const float* W1 = (const float*)d_in[8];
  const float* W2 = (const float*)d_in[9];
  const float* mw1 = (const float*)d_in[10];
  const float* mb1 = (const float*)d_in[11];
  const float* mw2 = (const float*)d_in[12];
  const float* mb2 = (const float*)d_in[13];
  const float* r = (const float*)d_in[14];
  float* out = (float*)d_out;

  char* w = (char*)d_ws;
  auto alloc = [&](size_t bytes) -> void* {
    void* p = (void*)w;
    w += (bytes + 255) & ~(size_t)255;
    return p;
  };
  int* deg = (int*)alloc((size_t)2 * kN * 4);
  int* cur = (int*)alloc((size_t)2 * kN * 4);
  int* srcs = (int*)alloc((size_t)2 * kEP * 4);
  float* eaw = (float*)alloc((size_t)2 * kEP * 4);
  size_t zbytes = (size_t)((char*)(eaw + 2 * kEP) - (char*)deg);
  int* off = (int*)alloc((size_t)2 * (kN + 1) * 4);
  float* h = (float*)alloc((size_t)2 * kN * kC1 * 4);
  float* Shat = (float*)alloc((size_t)kB * kNS * kNT * 4);
  float* pstatm = (float*)alloc((size_t)8 * kN * 4);
  float* pstatl = (float*)alloc((size_t)8 * kN * 4);
  float* rt = (float*)alloc((size_t)kN * kR * 4);
  float* PsAll = (float*)alloc((size_t)kSteps * kN * kR * 4);  // 2.6 MB
  float* Pt = (float*)alloc((size_t)kN * kC2 * 4);
  float* ct = (float*)alloc((size_t)kN * 4);
  float* part = (float*)alloc((size_t)8 * kChunkStride * 4);   // 2 MB
  float* outSL = out + (size_t)kB * kNS * kNT;

  hipMemsetAsync(deg, 0, zbytes, stream);
  k_hist<<<dim3(kE / 256, 2), 256, 0, stream>>>(ei_s, ei_t, deg);
  k_scan<<<2, 256, 0, stream>>>(deg, off, cur);
  k_scatter<<<dim3(kE / 256, 2), 256, 0, stream>>>(ei_s, ei_t, ea_s, ea_t, cur, srcs, eaw);
  k_pre<<<7168, 256, 0, stream>>>(x_s, x_t, r, srcs, eaw, off, W1, W2, mw1, mb1,
                                  h, PsAll);
  k_shat0<<<dim3(8, 8, kB), 256, 0, stream>>>(h, Shat, pstatm, pstatl);

  // one cooperative kernel for the whole step loop (40 boundaries -> 1)
  void* args[] = {&Shat, &pstatm, &pstatl, (void*)&r, (void*)&PsAll,
                  (void*)&srcs, (void*)&eaw, (void*)&off, (void*)&W2,
                  (void*)&mw1, (void*)&mw2, (void*)&mb2, &part, &rt, &Pt,
                  &ct, &out, &outSL};
  hipError_t err = hipLaunchCooperativeKernel((const void*)k_steps, dim3(512),
                                              dim3(256), args, 0, stream);
  if (err != hipSuccess) {
    // fallback: identical phases as separate kernels (r19 sequence)
    g_rt<<<dim3(16, 8, kB), 256, 0, stream>>>(Shat, pstatm, pstatl, r, part, 8, out);
    g_red<<<512, 256, 0, stream>>>(part, rt);
    for (int i = 0; i < kSteps; ++i) {
      g_psi2t<<<512, 256, 0, stream>>>(rt, srcs, eaw, off, W2, mw1, mw2, Pt, ct);
      g_upd<<<512, 256, 0, stream>>>(Shat, PsAll + (size_t)i * kN * kR, Pt, ct,
                                     mw2, mb2, pstatm, pstatl);
      if (i + 1 < kSteps) {
        g_rt<<<dim3(16, 8, kB), 256, 0, stream>>>(Shat, pstatm, pstatl,
                                                  r + (size_t)(i + 1) * kN * kR,
                                                  part, 2, nullptr);
        g_red<<<512, 256, 0, stream>>>(part, rt);
      }
    }
    g_out<<<512, 256, 0, stream>>>(Shat, pstatm, pstatl, outSL);
  }
}